// Round 1
// baseline (8254.346 us; speedup 1.0000x reference)
//
#include <hip/hip_runtime.h>

#define NNODES 50000
#define NEDGES 1600000
#define F 128

// ---------------- copy (init S = h_in) ----------------
__global__ __launch_bounds__(256) void copy_f4(const float4* __restrict__ in,
                                               float4* __restrict__ out, int n4) {
    int i = blockIdx.x * blockDim.x + threadIdx.x;
    int stride = gridDim.x * blockDim.x;
    for (; i < n4; i += stride) out[i] = in[i];
}

// ---------------- scatter-add: S[dst] += x[src] ----------------
// thread layout: 32 threads per edge (one float4 chunk each), 8 edges/block.
__global__ __launch_bounds__(256) void scatter_add(const float* __restrict__ x,
                                                   const int* __restrict__ src,
                                                   const int* __restrict__ dst,
                                                   float* __restrict__ sum) {
    const int e = blockIdx.x * 8 + (threadIdx.x >> 5);
    const int c = (threadIdx.x & 31) * 4;
    const int s = src[e];
    const int d = dst[e];
    const float4 v = *(const float4*)(x + (size_t)s * F + c);
    float* p = sum + (size_t)d * F + c;
    unsafeAtomicAdd(p + 0, v.x);
    unsafeAtomicAdd(p + 1, v.y);
    unsafeAtomicAdd(p + 2, v.z);
    unsafeAtomicAdd(p + 3, v.w);
}

// ---------------- MLP layer: out = relu?(S @ W + b), W is 128x128 ----------------
// Block: 256 threads. W staged in LDS (64 KB). 32 nodes/block in 4 passes of 8.
// Thread t handles node (t>>5) of the pass, output features (t&31)*4 .. +3.
__global__ __launch_bounds__(256, 2) void mlp128(const float* __restrict__ S,
                                                 const float* __restrict__ W,
                                                 const float* __restrict__ bias,
                                                 float* __restrict__ out, int n, int relu) {
    __shared__ float Wl[128 * 128];
    __shared__ float Sl[8][128];
    for (int i = threadIdx.x; i < 128 * 128 / 4; i += 256)
        ((float4*)Wl)[i] = ((const float4*)W)[i];
    const int og = (threadIdx.x & 31) * 4;  // output feature base
    const int nl = threadIdx.x >> 5;        // node index within pass (0..7)
    const float4 bv = *(const float4*)(bias + og);
    const int node0 = blockIdx.x * 32;
    __syncthreads();
    for (int pass = 0; pass < 4; ++pass) {
        const int nbase = node0 + pass * 8;
        {  // stage 8 input rows (1024 floats) coalesced
            const int r = threadIdx.x >> 5, cc = (threadIdx.x & 31) * 4;
            const int nn = nbase + r;
            float4 v = make_float4(0.f, 0.f, 0.f, 0.f);
            if (nn < n) v = *(const float4*)(S + (size_t)nn * F + cc);
            *(float4*)(&Sl[r][cc]) = v;
        }
        __syncthreads();
        const int node = nbase + nl;
        if (node < n) {
            float a0 = bv.x, a1 = bv.y, a2 = bv.z, a3 = bv.w;
#pragma unroll 4
            for (int k = 0; k < 128; ++k) {
                const float s = Sl[nl][k];
                const float4 w = *(const float4*)(&Wl[k * 128 + og]);
                a0 += s * w.x; a1 += s * w.y; a2 += s * w.z; a3 += s * w.w;
            }
            if (relu) {
                a0 = fmaxf(a0, 0.f); a1 = fmaxf(a1, 0.f);
                a2 = fmaxf(a2, 0.f); a3 = fmaxf(a3, 0.f);
            }
            *(float4*)(out + (size_t)node * F + og) = make_float4(a0, a1, a2, a3);
        }
        __syncthreads();
    }
}

// ---------------- head: out = S @ W3 + b3, W3 is 128x2 ----------------
// One wave per node; lane l covers input features 2l, 2l+1; shuffle-reduce.
__global__ __launch_bounds__(256) void head2(const float* __restrict__ S,
                                             const float* __restrict__ W,
                                             const float* __restrict__ b,
                                             float* __restrict__ out, int n) {
    const int wid = (blockIdx.x * blockDim.x + threadIdx.x) >> 6;  // node
    const int lane = threadIdx.x & 63;
    if (wid >= n) return;
    const float2 s = *(const float2*)(S + (size_t)wid * F + lane * 2);
    const float2 w0 = *(const float2*)(W + (2 * lane + 0) * 2);
    const float2 w1 = *(const float2*)(W + (2 * lane + 1) * 2);
    float a0 = s.x * w0.x + s.y * w1.x;
    float a1 = s.x * w0.y + s.y * w1.y;
#pragma unroll
    for (int off = 32; off; off >>= 1) {
        a0 += __shfl_xor(a0, off);
        a1 += __shfl_xor(a1, off);
    }
    if (lane == 0) {
        out[wid * 2 + 0] = a0 + b[0];
        out[wid * 2 + 1] = a1 + b[1];
    }
}

extern "C" void kernel_launch(void* const* d_in, const int* in_sizes, int n_in,
                              void* d_out, int out_size, void* d_ws, size_t ws_size,
                              hipStream_t stream) {
    const float* x  = (const float*)d_in[0];
    const int* ei   = (const int*)d_in[1];
    const int* src  = ei;            // edge_index[0]
    const int* dst  = ei + NEDGES;   // edge_index[1]
    const float* W1 = (const float*)d_in[2];
    const float* b1 = (const float*)d_in[3];
    const float* W2 = (const float*)d_in[4];
    const float* b2 = (const float*)d_in[5];
    const float* W3 = (const float*)d_in[6];
    const float* b3 = (const float*)d_in[7];
    float* out = (float*)d_out;

    float* S = (float*)d_ws;                     // 50000*128 f32 = 25.6 MB
    float* H = S + (size_t)NNODES * F;           // 25.6 MB

    const int n4 = NNODES * F / 4;               // 1.6M float4
    const int copyBlocks = 2048;
    const int scatBlocks = NEDGES / 8;           // 200000
    const int mlpBlocks = (NNODES + 31) / 32;    // 1563
    const int headBlocks = (NNODES + 3) / 4;     // 4 waves/block

    // ---- layer 1 ----
    copy_f4<<<copyBlocks, 256, 0, stream>>>((const float4*)x, (float4*)S, n4);
    scatter_add<<<scatBlocks, 256, 0, stream>>>(x, src, dst, S);
    mlp128<<<mlpBlocks, 256, 0, stream>>>(S, W1, b1, H, NNODES, 1);

    // ---- layer 2 ----
    copy_f4<<<copyBlocks, 256, 0, stream>>>((const float4*)H, (float4*)S, n4);
    scatter_add<<<scatBlocks, 256, 0, stream>>>(H, src, dst, S);
    mlp128<<<mlpBlocks, 256, 0, stream>>>(S, W2, b2, H, NNODES, 1);

    // ---- layer 3 (head) ----
    copy_f4<<<copyBlocks, 256, 0, stream>>>((const float4*)H, (float4*)S, n4);
    scatter_add<<<scatBlocks, 256, 0, stream>>>(H, src, dst, S);
    head2<<<headBlocks, 256, 0, stream>>>(S, W3, b3, out, NNODES);
}

// Round 2
// 833.108 us; speedup vs baseline: 9.9079x; 9.9079x over previous
//
#include <hip/hip_runtime.h>

#define NNODES 50000
#define NEDGES 1600000
#define F 128
#define SCAN_PER 49  // 1024 threads * 49 >= 50000

// ---------------- CSR build step 1: histogram of dst ----------------
__global__ __launch_bounds__(256) void hist_dst(const int* __restrict__ dst,
                                                int* __restrict__ deg) {
    int i = blockIdx.x * blockDim.x + threadIdx.x;
    int stride = gridDim.x * blockDim.x;
    for (; i < NEDGES; i += stride) atomicAdd(&deg[dst[i]], 1);
}

// ---------------- CSR build step 2: exclusive scan (single block, 1024 thr) ----
// In-place: deg[] -> exclusive offsets; also copies into pos[]; off[n]=NEDGES.
__global__ __launch_bounds__(1024) void scan50k(int* __restrict__ off,
                                                int* __restrict__ pos, int n, int total) {
    __shared__ int wsum[16];
    const int t = threadIdx.x;
    const int lane = t & 63;
    const int w = t >> 6;
    const int base = t * SCAN_PER;
    int lsum = 0;
    for (int k = 0; k < SCAN_PER; ++k) {
        int i = base + k;
        if (i < n) lsum += off[i];
    }
    // wave-inclusive scan of lsum
    int inc = lsum;
#pragma unroll
    for (int o = 1; o <= 32; o <<= 1) {
        int u = __shfl_up(inc, o);
        if (lane >= o) inc += u;
    }
    if (lane == 63) wsum[w] = inc;
    __syncthreads();
    if (w == 0 && lane < 16) {
        int v = wsum[lane];
#pragma unroll
        for (int o = 1; o <= 8; o <<= 1) {
            int u = __shfl_up(v, o);
            if (lane >= o) v += u;
        }
        wsum[lane] = v;
    }
    __syncthreads();
    int run = inc - lsum + (w > 0 ? wsum[w - 1] : 0);
    for (int k = 0; k < SCAN_PER; ++k) {
        int i = base + k;
        if (i < n) {
            int old = off[i];
            off[i] = run;
            pos[i] = run;
            run += old;
        }
    }
    if (t == 0) off[n] = total;
}

// ---------------- CSR build step 3: scatter src ids into dst-grouped order ----
__global__ __launch_bounds__(256) void fill_csr(const int* __restrict__ src,
                                                const int* __restrict__ dst,
                                                int* __restrict__ pos,
                                                int* __restrict__ ssrc) {
    int i = blockIdx.x * blockDim.x + threadIdx.x;
    int stride = gridDim.x * blockDim.x;
    for (; i < NEDGES; i += stride) {
        int p = atomicAdd(&pos[dst[i]], 1);
        ssrc[p] = src[i];
    }
}

// ---------------- aggregation: S[i] = h[i] + sum_{e in N(i)} h[ssrc[e]] ------
// One wave per node; lane l holds features 2l, 2l+1 (float2).
__global__ __launch_bounds__(256) void agg_gather(const float* __restrict__ h,
                                                  const int* __restrict__ off,
                                                  const int* __restrict__ ssrc,
                                                  float* __restrict__ S, int n) {
    const int wid = (blockIdx.x * blockDim.x + threadIdx.x) >> 6;
    const int lane = threadIdx.x & 63;
    if (wid >= n) return;
    const int e0 = off[wid], e1 = off[wid + 1];
    const size_t lo = (size_t)lane * 2;
    float2 acc = *(const float2*)(h + (size_t)wid * F + lo);
    int e = e0;
    for (; e + 4 <= e1; e += 4) {
        const int s0 = ssrc[e], s1 = ssrc[e + 1], s2 = ssrc[e + 2], s3 = ssrc[e + 3];
        const float2 v0 = *(const float2*)(h + (size_t)s0 * F + lo);
        const float2 v1 = *(const float2*)(h + (size_t)s1 * F + lo);
        const float2 v2 = *(const float2*)(h + (size_t)s2 * F + lo);
        const float2 v3 = *(const float2*)(h + (size_t)s3 * F + lo);
        acc.x += v0.x + v1.x + v2.x + v3.x;
        acc.y += v0.y + v1.y + v2.y + v3.y;
    }
    for (; e < e1; ++e) {
        const float2 v = *(const float2*)(h + (size_t)ssrc[e] * F + lo);
        acc.x += v.x;
        acc.y += v.y;
    }
    *(float2*)(S + (size_t)wid * F + lo) = acc;
}

// ---------------- MLP layer: out = relu?(S @ W + b), W is 128x128 ----------------
__global__ __launch_bounds__(256, 2) void mlp128(const float* __restrict__ S,
                                                 const float* __restrict__ W,
                                                 const float* __restrict__ bias,
                                                 float* __restrict__ out, int n, int relu) {
    __shared__ float Wl[128 * 128];
    __shared__ float Sl[8][128];
    for (int i = threadIdx.x; i < 128 * 128 / 4; i += 256)
        ((float4*)Wl)[i] = ((const float4*)W)[i];
    const int og = (threadIdx.x & 31) * 4;
    const int nl = threadIdx.x >> 5;
    const float4 bv = *(const float4*)(bias + og);
    const int node0 = blockIdx.x * 32;
    __syncthreads();
    for (int pass = 0; pass < 4; ++pass) {
        const int nbase = node0 + pass * 8;
        {
            const int r = threadIdx.x >> 5, cc = (threadIdx.x & 31) * 4;
            const int nn = nbase + r;
            float4 v = make_float4(0.f, 0.f, 0.f, 0.f);
            if (nn < n) v = *(const float4*)(S + (size_t)nn * F + cc);
            *(float4*)(&Sl[r][cc]) = v;
        }
        __syncthreads();
        const int node = nbase + nl;
        if (node < n) {
            float a0 = bv.x, a1 = bv.y, a2 = bv.z, a3 = bv.w;
#pragma unroll 4
            for (int k = 0; k < 128; ++k) {
                const float s = Sl[nl][k];
                const float4 w = *(const float4*)(&Wl[k * 128 + og]);
                a0 += s * w.x; a1 += s * w.y; a2 += s * w.z; a3 += s * w.w;
            }
            if (relu) {
                a0 = fmaxf(a0, 0.f); a1 = fmaxf(a1, 0.f);
                a2 = fmaxf(a2, 0.f); a3 = fmaxf(a3, 0.f);
            }
            *(float4*)(out + (size_t)node * F + og) = make_float4(a0, a1, a2, a3);
        }
        __syncthreads();
    }
}

// ---------------- head: out = S @ W3 + b3, W3 is 128x2 ----------------
__global__ __launch_bounds__(256) void head2(const float* __restrict__ S,
                                             const float* __restrict__ W,
                                             const float* __restrict__ b,
                                             float* __restrict__ out, int n) {
    const int wid = (blockIdx.x * blockDim.x + threadIdx.x) >> 6;
    const int lane = threadIdx.x & 63;
    if (wid >= n) return;
    const float2 s = *(const float2*)(S + (size_t)wid * F + lane * 2);
    const float2 w0 = *(const float2*)(W + (2 * lane + 0) * 2);
    const float2 w1 = *(const float2*)(W + (2 * lane + 1) * 2);
    float a0 = s.x * w0.x + s.y * w1.x;
    float a1 = s.x * w0.y + s.y * w1.y;
#pragma unroll
    for (int off = 32; off; off >>= 1) {
        a0 += __shfl_xor(a0, off);
        a1 += __shfl_xor(a1, off);
    }
    if (lane == 0) {
        out[wid * 2 + 0] = a0 + b[0];
        out[wid * 2 + 1] = a1 + b[1];
    }
}

extern "C" void kernel_launch(void* const* d_in, const int* in_sizes, int n_in,
                              void* d_out, int out_size, void* d_ws, size_t ws_size,
                              hipStream_t stream) {
    const float* x  = (const float*)d_in[0];
    const int* ei   = (const int*)d_in[1];
    const int* src  = ei;            // edge_index[0]
    const int* dst  = ei + NEDGES;   // edge_index[1]
    const float* W1 = (const float*)d_in[2];
    const float* b1 = (const float*)d_in[3];
    const float* W2 = (const float*)d_in[4];
    const float* b2 = (const float*)d_in[5];
    const float* W3 = (const float*)d_in[6];
    const float* b3 = (const float*)d_in[7];
    float* out = (float*)d_out;

    float* S = (float*)d_ws;                    // 25.6 MB
    float* H = S + (size_t)NNODES * F;          // 25.6 MB
    int* off  = (int*)(H + (size_t)NNODES * F); // NNODES+1
    int* pos  = off + NNODES + 1;               // NNODES
    int* ssrc = pos + NNODES;                   // NEDGES (6.4 MB)

    // ---- CSR build (counting sort by dst) ----
    hipMemsetAsync(off, 0, (size_t)NNODES * sizeof(int), stream);
    hist_dst<<<2048, 256, 0, stream>>>(dst, off);
    scan50k<<<1, 1024, 0, stream>>>(off, pos, NNODES, NEDGES);
    fill_csr<<<2048, 256, 0, stream>>>(src, dst, pos, ssrc);

    const int aggBlocks = (NNODES + 3) / 4;     // 4 waves/block
    const int mlpBlocks = (NNODES + 31) / 32;
    const int headBlocks = (NNODES + 3) / 4;

    // ---- layer 1 ----
    agg_gather<<<aggBlocks, 256, 0, stream>>>(x, off, ssrc, S, NNODES);
    mlp128<<<mlpBlocks, 256, 0, stream>>>(S, W1, b1, H, NNODES, 1);

    // ---- layer 2 ----
    agg_gather<<<aggBlocks, 256, 0, stream>>>(H, off, ssrc, S, NNODES);
    mlp128<<<mlpBlocks, 256, 0, stream>>>(S, W2, b2, H, NNODES, 1);

    // ---- layer 3 (head) ----
    agg_gather<<<aggBlocks, 256, 0, stream>>>(H, off, ssrc, S, NNODES);
    head2<<<headBlocks, 256, 0, stream>>>(S, W3, b3, out, NNODES);
}

// Round 3
// 579.148 us; speedup vs baseline: 14.2526x; 1.4385x over previous
//
#include <hip/hip_runtime.h>

#define NNODES 50000
#define NEDGES 1600000
#define F 128
#define SCAN_PER 49  // 1024 threads * 49 >= 50000

typedef __attribute__((ext_vector_type(8))) short bf16x8;
typedef __attribute__((ext_vector_type(4))) float f32x4;

__device__ inline unsigned short f2bf(float f) {
    union { float f; unsigned u; } v; v.f = f;
    unsigned r = v.u + 0x7FFF + ((v.u >> 16) & 1);  // RNE
    return (unsigned short)(r >> 16);
}
__device__ inline float2 up2(ushort2 h) {
    union { unsigned u; float f; } a, b;
    a.u = ((unsigned)h.x) << 16; b.u = ((unsigned)h.y) << 16;
    return make_float2(a.f, b.f);
}

// ---------------- f32 -> bf16 feature conversion ----------------
__global__ __launch_bounds__(256) void cvt_bf16(const float4* __restrict__ in,
                                                ushort4* __restrict__ out, int n4) {
    int i = blockIdx.x * blockDim.x + threadIdx.x;
    int stride = gridDim.x * blockDim.x;
    for (; i < n4; i += stride) {
        float4 v = in[i];
        ushort4 o;
        o.x = f2bf(v.x); o.y = f2bf(v.y); o.z = f2bf(v.z); o.w = f2bf(v.w);
        out[i] = o;
    }
}

// ---------------- pack W (128x128 f32 row-major) into MFMA B-fragment order ----
// frag(s,n), lane l, j=0..7:  B[k = s*32 + (l>>4)*8 + j][c = n*16 + (l&15)]
// stored at Wfrag[ ((s*8+n)*64 + l)*8 + j ]
__global__ __launch_bounds__(256) void wprep(const float* __restrict__ W,
                                             unsigned short* __restrict__ Wfrag) {
    const int id = blockIdx.x * 256 + threadIdx.x;  // 0..2047
    if (id >= 2048) return;
    const int l = id & 63, nn = (id >> 6) & 7, s = id >> 9;
    const int c = nn * 16 + (l & 15);
    const int k0 = s * 32 + (l >> 4) * 8;
    ushort4 lo, hi;
    lo.x = f2bf(W[(k0 + 0) * F + c]); lo.y = f2bf(W[(k0 + 1) * F + c]);
    lo.z = f2bf(W[(k0 + 2) * F + c]); lo.w = f2bf(W[(k0 + 3) * F + c]);
    hi.x = f2bf(W[(k0 + 4) * F + c]); hi.y = f2bf(W[(k0 + 5) * F + c]);
    hi.z = f2bf(W[(k0 + 6) * F + c]); hi.w = f2bf(W[(k0 + 7) * F + c]);
    ushort4* p = (ushort4*)(Wfrag + (size_t)id * 8);
    p[0] = lo; p[1] = hi;
}

// ---------------- CSR build ----------------
__global__ __launch_bounds__(256) void hist_dst(const int* __restrict__ dst,
                                                int* __restrict__ deg) {
    int i = blockIdx.x * blockDim.x + threadIdx.x;
    int stride = gridDim.x * blockDim.x;
    for (; i < NEDGES; i += stride) atomicAdd(&deg[dst[i]], 1);
}

__global__ __launch_bounds__(1024) void scan50k(int* __restrict__ off,
                                                int* __restrict__ pos, int n, int total) {
    __shared__ int wsum[16];
    const int t = threadIdx.x;
    const int lane = t & 63;
    const int w = t >> 6;
    const int base = t * SCAN_PER;
    int lsum = 0;
    for (int k = 0; k < SCAN_PER; ++k) {
        int i = base + k;
        if (i < n) lsum += off[i];
    }
    int inc = lsum;
#pragma unroll
    for (int o = 1; o <= 32; o <<= 1) {
        int u = __shfl_up(inc, o);
        if (lane >= o) inc += u;
    }
    if (lane == 63) wsum[w] = inc;
    __syncthreads();
    if (w == 0 && lane < 16) {
        int v = wsum[lane];
#pragma unroll
        for (int o = 1; o <= 8; o <<= 1) {
            int u = __shfl_up(v, o);
            if (lane >= o) v += u;
        }
        wsum[lane] = v;
    }
    __syncthreads();
    int run = inc - lsum + (w > 0 ? wsum[w - 1] : 0);
    for (int k = 0; k < SCAN_PER; ++k) {
        int i = base + k;
        if (i < n) {
            int old = off[i];
            off[i] = run;
            pos[i] = run;
            run += old;
        }
    }
    if (t == 0) off[n] = total;
}

__global__ __launch_bounds__(256) void fill_csr(const int* __restrict__ src,
                                                const int* __restrict__ dst,
                                                int* __restrict__ pos,
                                                int* __restrict__ ssrc) {
    int i = blockIdx.x * blockDim.x + threadIdx.x;
    int stride = gridDim.x * blockDim.x;
    for (; i < NEDGES; i += stride) {
        int p = atomicAdd(&pos[dst[i]], 1);
        ssrc[p] = src[i];
    }
}

// ---------------- aggregation (bf16): S[i] = h[i] + sum h[ssrc[e]] ------
// One wave per node; lane l holds features 2l,2l+1 (ushort2, 4B -> 256B/row coalesced).
__global__ __launch_bounds__(256) void agg_bf16(const ushort2* __restrict__ h,
                                                const int* __restrict__ off,
                                                const int* __restrict__ ssrc,
                                                ushort2* __restrict__ S, int n) {
    const int wid = (blockIdx.x * blockDim.x + threadIdx.x) >> 6;
    const int lane = threadIdx.x & 63;
    if (wid >= n) return;
    const int e0 = off[wid], e1 = off[wid + 1];
    float2 acc = up2(h[(size_t)wid * 64 + lane]);
    int e = e0;
    for (; e + 4 <= e1; e += 4) {
        const int s0 = ssrc[e], s1 = ssrc[e + 1], s2 = ssrc[e + 2], s3 = ssrc[e + 3];
        const float2 v0 = up2(h[(size_t)s0 * 64 + lane]);
        const float2 v1 = up2(h[(size_t)s1 * 64 + lane]);
        const float2 v2 = up2(h[(size_t)s2 * 64 + lane]);
        const float2 v3 = up2(h[(size_t)s3 * 64 + lane]);
        acc.x += v0.x + v1.x + v2.x + v3.x;
        acc.y += v0.y + v1.y + v2.y + v3.y;
    }
    for (; e < e1; ++e) {
        const float2 v = up2(h[(size_t)ssrc[e] * 64 + lane]);
        acc.x += v.x;
        acc.y += v.y;
    }
    ushort2 o;
    o.x = f2bf(acc.x); o.y = f2bf(acc.y);
    S[(size_t)wid * 64 + lane] = o;
}

// ---------------- MFMA MLP: Hb = relu?(Sb @ W + b)  [M=n, N=128, K=128] -----
// 4 waves/block, 16 nodes/wave, no LDS. A from global (row = l&15, k = (l>>4)*8+j),
// B from pre-packed Wfrag (coalesced, L2-hot). C/D: col=l&15, row=(l>>4)*4+reg.
__global__ __launch_bounds__(256) void mlp_mfma(const unsigned short* __restrict__ Sb,
                                                const unsigned short* __restrict__ Wfrag,
                                                const float* __restrict__ bias,
                                                unsigned short* __restrict__ Hb,
                                                int n, int relu) {
    const int wave = threadIdx.x >> 6, lane = threadIdx.x & 63;
    const int base = blockIdx.x * 64 + wave * 16;
    const int r16 = lane & 15, hi = lane >> 4;
    int arow = base + r16;
    if (arow >= n) arow = n - 1;  // clamp loads; stores masked below
    const unsigned short* Arow = Sb + (size_t)arow * F;

    f32x4 acc[8];
#pragma unroll
    for (int i = 0; i < 8; ++i) acc[i] = (f32x4){0.f, 0.f, 0.f, 0.f};

#pragma unroll
    for (int s = 0; s < 4; ++s) {
        const bf16x8 a = *(const bf16x8*)(Arow + s * 32 + hi * 8);
#pragma unroll
        for (int nn = 0; nn < 8; ++nn) {
            const bf16x8 b = *(const bf16x8*)(Wfrag + ((size_t)(s * 8 + nn) * 64 + lane) * 8);
            acc[nn] = __builtin_amdgcn_mfma_f32_16x16x32_bf16(a, b, acc[nn], 0, 0, 0);
        }
    }

#pragma unroll
    for (int nn = 0; nn < 8; ++nn) {
        const int col = nn * 16 + r16;
        const float bv = bias[col];
#pragma unroll
        for (int r = 0; r < 4; ++r) {
            const int row = base + hi * 4 + r;
            if (row < n) {
                float v = acc[nn][r] + bv;
                if (relu) v = fmaxf(v, 0.f);
                Hb[(size_t)row * F + col] = f2bf(v);
            }
        }
    }
}

// ---------------- layer-3 transform (before agg, by linearity): y = h @ W3 ----
__global__ __launch_bounds__(256) void head_t(const ushort2* __restrict__ Hb,
                                              const float4* __restrict__ W3,
                                              float2* __restrict__ y, int n) {
    const int wid = (blockIdx.x * blockDim.x + threadIdx.x) >> 6;
    const int lane = threadIdx.x & 63;
    if (wid >= n) return;
    const float2 h = up2(Hb[(size_t)wid * 64 + lane]);
    const float4 w = W3[lane];  // W3[2l][0..1], W3[2l+1][0..1]
    float a0 = h.x * w.x + h.y * w.z;
    float a1 = h.x * w.y + h.y * w.w;
#pragma unroll
    for (int o = 32; o; o >>= 1) {
        a0 += __shfl_xor(a0, o);
        a1 += __shfl_xor(a1, o);
    }
    if (lane == 0) y[wid] = make_float2(a0, a1);
}

// ---------------- layer-3 aggregation on 2-dim y: out = y + agg(y) + b3 ------
__global__ __launch_bounds__(256) void agg3(const float2* __restrict__ y,
                                            const int* __restrict__ off,
                                            const int* __restrict__ ssrc,
                                            const float* __restrict__ b3,
                                            float2* __restrict__ out, int n) {
    const int i = blockIdx.x * blockDim.x + threadIdx.x;
    if (i >= n) return;
    float2 acc = y[i];
    const int e1 = off[i + 1];
    for (int e = off[i]; e < e1; ++e) {
        const float2 v = y[ssrc[e]];
        acc.x += v.x;
        acc.y += v.y;
    }
    out[i] = make_float2(acc.x + b3[0], acc.y + b3[1]);
}

extern "C" void kernel_launch(void* const* d_in, const int* in_sizes, int n_in,
                              void* d_out, int out_size, void* d_ws, size_t ws_size,
                              hipStream_t stream) {
    const float* x  = (const float*)d_in[0];
    const int* ei   = (const int*)d_in[1];
    const int* src  = ei;
    const int* dst  = ei + NEDGES;
    const float* W1 = (const float*)d_in[2];
    const float* b1 = (const float*)d_in[3];
    const float* W2 = (const float*)d_in[4];
    const float* b2 = (const float*)d_in[5];
    const float* W3 = (const float*)d_in[6];
    const float* b3 = (const float*)d_in[7];
    float* out = (float*)d_out;

    char* ws = (char*)d_ws;
    const size_t featB = (size_t)NNODES * F * 2;  // 12.8 MB
    unsigned short* xb = (unsigned short*)ws;                 // bf16 x; reused as H2 output
    unsigned short* Sb = (unsigned short*)(ws + featB);       // aggregated (bf16)
    unsigned short* Hb = (unsigned short*)(ws + 2 * featB);   // layer-1 output
    float* y3          = (float*)(ws + 3 * featB);            // 50000x2 f32
    unsigned short* Wf1 = (unsigned short*)(ws + 3 * featB + 400000);
    unsigned short* Wf2 = Wf1 + 2048 * 8;
    int* off  = (int*)(Wf2 + 2048 * 8);
    int* pos  = off + NNODES + 1;
    int* ssrc = pos + NNODES;

    // ---- prep: bf16 conversion + W fragment packing + CSR build ----
    cvt_bf16<<<1024, 256, 0, stream>>>((const float4*)x, (ushort4*)xb, NNODES * F / 4);
    wprep<<<8, 256, 0, stream>>>(W1, Wf1);
    wprep<<<8, 256, 0, stream>>>(W2, Wf2);
    hipMemsetAsync(off, 0, (size_t)NNODES * sizeof(int), stream);
    hist_dst<<<2048, 256, 0, stream>>>(dst, off);
    scan50k<<<1, 1024, 0, stream>>>(off, pos, NNODES, NEDGES);
    fill_csr<<<2048, 256, 0, stream>>>(src, dst, pos, ssrc);

    const int aggBlocks = (NNODES + 3) / 4;      // 4 waves/block
    const int mlpBlocks = (NNODES + 63) / 64;    // 64 nodes/block

    // ---- layer 1 ----
    agg_bf16<<<aggBlocks, 256, 0, stream>>>((const ushort2*)xb, off, ssrc, (ushort2*)Sb, NNODES);
    mlp_mfma<<<mlpBlocks, 256, 0, stream>>>(Sb, Wf1, b1, Hb, NNODES, 1);

    // ---- layer 2 (output into xb buffer, no longer needed) ----
    agg_bf16<<<aggBlocks, 256, 0, stream>>>((const ushort2*)Hb, off, ssrc, (ushort2*)Sb, NNODES);
    mlp_mfma<<<mlpBlocks, 256, 0, stream>>>(Sb, Wf2, b2, xb, NNODES, 1);

    // ---- layer 3: transform first (linearity), then 2-dim aggregation ----
    head_t<<<aggBlocks, 256, 0, stream>>>((const ushort2*)xb, (const float4*)W3, (float2*)y3, NNODES);
    agg3<<<(NNODES + 255) / 256, 256, 0, stream>>>((const float2*)y3, off, ssrc, b3, (float2*)out, NNODES);
}

// Round 5
// 314.458 us; speedup vs baseline: 26.2495x; 1.8417x over previous
//
#include <hip/hip_runtime.h>

#define NNODES 50000
#define NEDGES 1600000
#define F 128

#define NB 128        // coarse buckets
#define BSH 391       // nodes per bucket (128*391 = 50048 >= 50000)
#define BCAP 13312    // slots per bucket (mean 12500, +7 sigma)
#define EPT 10        // edges per thread in bucketA (625 * 2560 = 1600000 exactly)

typedef __attribute__((ext_vector_type(8))) short bf16x8;
typedef __attribute__((ext_vector_type(4))) float f32x4;

__device__ inline unsigned short f2bf(float f) {
    union { float f; unsigned u; } v; v.f = f;
    unsigned r = v.u + 0x7FFF + ((v.u >> 16) & 1);  // RNE
    return (unsigned short)(r >> 16);
}
__device__ inline float2 up2(ushort2 h) {
    union { unsigned u; float f; } a, b;
    a.u = ((unsigned)h.x) << 16; b.u = ((unsigned)h.y) << 16;
    return make_float2(a.f, b.f);
}

// ---------------- f32 -> bf16 feature conversion ----------------
__global__ __launch_bounds__(256) void cvt_bf16(const float4* __restrict__ in,
                                                ushort4* __restrict__ out, int n4) {
    int i = blockIdx.x * blockDim.x + threadIdx.x;
    int stride = gridDim.x * blockDim.x;
    for (; i < n4; i += stride) {
        float4 v = in[i];
        ushort4 o;
        o.x = f2bf(v.x); o.y = f2bf(v.y); o.z = f2bf(v.z); o.w = f2bf(v.w);
        out[i] = o;
    }
}

// ---------------- pack W1,W2 into MFMA B-fragment order (one launch) --------
// frag(s,n), lane l, j=0..7:  B[k = s*32 + (l>>4)*8 + j][c = n*16 + (l&15)]
__global__ __launch_bounds__(256) void wprep2(const float* __restrict__ W1,
                                              const float* __restrict__ W2,
                                              unsigned short* __restrict__ Wf1,
                                              unsigned short* __restrict__ Wf2) {
    int id = blockIdx.x * 256 + threadIdx.x;  // 0..4095
    const float* W = (id < 2048) ? W1 : W2;
    unsigned short* Wf = (id < 2048) ? Wf1 : Wf2;
    id &= 2047;
    const int l = id & 63, nn = (id >> 6) & 7, s = id >> 9;
    const int c = nn * 16 + (l & 15);
    const int k0 = s * 32 + (l >> 4) * 8;
    ushort4 lo, hi;
    lo.x = f2bf(W[(k0 + 0) * F + c]); lo.y = f2bf(W[(k0 + 1) * F + c]);
    lo.z = f2bf(W[(k0 + 2) * F + c]); lo.w = f2bf(W[(k0 + 3) * F + c]);
    hi.x = f2bf(W[(k0 + 4) * F + c]); hi.y = f2bf(W[(k0 + 5) * F + c]);
    hi.z = f2bf(W[(k0 + 6) * F + c]); hi.w = f2bf(W[(k0 + 7) * F + c]);
    ushort4* p = (ushort4*)(Wf + (size_t)id * 8);
    p[0] = lo; p[1] = hi;
}

// ---------------- phase A: multi-split edges into 128 coarse buckets --------
// rec = (src << 9) | (dst % BSH); bucket = dst / BSH.
// Per-tile LDS histogram -> one global atomicAdd per (tile,bucket) -> chunked
// writes from a single CU (full-line writebacks instead of 64B/edge).
__global__ __launch_bounds__(256) void bucketA(const int* __restrict__ src,
                                               const int* __restrict__ dst,
                                               unsigned* __restrict__ E1,
                                               int* __restrict__ gcnt) {
    __shared__ unsigned hist[NB];
    __shared__ unsigned start[NB];
    const int t = threadIdx.x;
    if (t < NB) hist[t] = 0;
    __syncthreads();
    const int base = blockIdx.x * (256 * EPT);
    unsigned rec[EPT]; int bkt[EPT];
#pragma unroll
    for (int k = 0; k < EPT; ++k) {
        const int i = base + k * 256 + t;  // coalesced
        const int s = src[i], d = dst[i];
        const int b = d / BSH;             // const divide -> magic mul
        rec[k] = ((unsigned)s << 9) | (unsigned)(d - b * BSH);
        bkt[k] = b;
        atomicAdd(&hist[b], 1u);
    }
    __syncthreads();
    if (t < NB) {
        unsigned h = hist[t];
        start[t] = h ? (unsigned)atomicAdd(&gcnt[t], (int)h) : 0u;
        hist[t] = 0;  // reuse as intra-tile cursor
    }
    __syncthreads();
#pragma unroll
    for (int k = 0; k < EPT; ++k) {
        const int b = bkt[k];
        const unsigned p = start[b] + atomicAdd(&hist[b], 1u);
        if (p < BCAP) E1[(size_t)b * BCAP + p] = rec[k];
    }
}

// ---------------- scan of 128 bucket counts (one wave) ----------------
__global__ __launch_bounds__(64) void scanB(const int* __restrict__ gcnt,
                                            int* __restrict__ bstart,
                                            int* __restrict__ off) {
    const int lane = threadIdx.x;
    int a0 = gcnt[lane * 2], a1 = gcnt[lane * 2 + 1];
    int s = a0 + a1, inc = s;
#pragma unroll
    for (int o = 1; o <= 32; o <<= 1) {
        int u = __shfl_up(inc, o);
        if (lane >= o) inc += u;
    }
    int excl = inc - s;
    bstart[lane * 2] = excl;
    bstart[lane * 2 + 1] = excl + a0;
    if (lane == 63) off[NNODES] = NEDGES;
}

// ---------------- phase B: in-LDS counting sort per bucket -> exact CSR -----
__global__ __launch_bounds__(256) void bucketB(const unsigned* __restrict__ E1,
                                               const int* __restrict__ gcnt,
                                               const int* __restrict__ bstart,
                                               int* __restrict__ off,
                                               unsigned short* __restrict__ ssrc) {
    __shared__ int cnt[BSH];
    __shared__ int cur[BSH];
    __shared__ int wtot[4];
    const int b = blockIdx.x, t = threadIdx.x;
    const int ne = min(gcnt[b], BCAP);
    const int ebase = bstart[b];
    const unsigned* E = E1 + (size_t)b * BCAP;
    for (int i = t; i < BSH; i += 256) cnt[i] = 0;
    __syncthreads();
    for (int i = t; i < ne; i += 256) atomicAdd(&cnt[E[i] & 511], 1);
    __syncthreads();
    // exclusive scan of cnt[0..BSH), 2 elements per thread
    const int i0 = t * 2, i1 = t * 2 + 1;
    const int a0 = (i0 < BSH) ? cnt[i0] : 0;
    const int a1 = (i1 < BSH) ? cnt[i1] : 0;
    const int s = a0 + a1;
    int inc = s;
    const int lane = t & 63, w = t >> 6;
#pragma unroll
    for (int o = 1; o <= 32; o <<= 1) {
        int u = __shfl_up(inc, o);
        if (lane >= o) inc += u;
    }
    if (lane == 63) wtot[w] = inc;
    __syncthreads();
    int woff = 0;
    for (int k = 0; k < w; ++k) woff += wtot[k];  // w <= 3
    const int excl = woff + inc - s;
    if (i0 < BSH) {
        cur[i0] = excl;
        const int n = b * BSH + i0;
        if (n < NNODES) off[n] = ebase + excl;
    }
    if (i1 < BSH) {
        cur[i1] = excl + a0;
        const int n = b * BSH + i1;
        if (n < NNODES) off[n] = ebase + excl + a0;
    }
    __syncthreads();
    for (int i = t; i < ne; i += 256) {
        const unsigned rec = E[i];
        const int r = atomicAdd(&cur[rec & 511], 1);
        ssrc[ebase + r] = (unsigned short)(rec >> 9);
    }
}

// ---------------- aggregation (bf16): S[i] = h[i] + sum h[ssrc[e]] ------
__global__ __launch_bounds__(256) void agg_bf16(const ushort2* __restrict__ h,
                                                const int* __restrict__ off,
                                                const unsigned short* __restrict__ ssrc,
                                                ushort2* __restrict__ S, int n) {
    const int wid = (blockIdx.x * blockDim.x + threadIdx.x) >> 6;
    const int lane = threadIdx.x & 63;
    if (wid >= n) return;
    const int e0 = off[wid], e1 = off[wid + 1];
    float2 acc = up2(h[(size_t)wid * 64 + lane]);
    int e = e0;
    for (; e + 4 <= e1; e += 4) {
        const int s0 = ssrc[e], s1 = ssrc[e + 1], s2 = ssrc[e + 2], s3 = ssrc[e + 3];
        const float2 v0 = up2(h[(size_t)s0 * 64 + lane]);
        const float2 v1 = up2(h[(size_t)s1 * 64 + lane]);
        const float2 v2 = up2(h[(size_t)s2 * 64 + lane]);
        const float2 v3 = up2(h[(size_t)s3 * 64 + lane]);
        acc.x += v0.x + v1.x + v2.x + v3.x;
        acc.y += v0.y + v1.y + v2.y + v3.y;
    }
    for (; e < e1; ++e) {
        const float2 v = up2(h[(size_t)ssrc[e] * 64 + lane]);
        acc.x += v.x;
        acc.y += v.y;
    }
    ushort2 o;
    o.x = f2bf(acc.x); o.y = f2bf(acc.y);
    S[(size_t)wid * 64 + lane] = o;
}

// ---------------- MFMA MLP: Hb = relu?(Sb @ W + b)  [M=n, N=128, K=128] -----
__global__ __launch_bounds__(256) void mlp_mfma(const unsigned short* __restrict__ Sb,
                                                const unsigned short* __restrict__ Wfrag,
                                                const float* __restrict__ bias,
                                                unsigned short* __restrict__ Hb,
                                                int n, int relu) {
    const int wave = threadIdx.x >> 6, lane = threadIdx.x & 63;
    const int base = blockIdx.x * 64 + wave * 16;
    const int r16 = lane & 15, hi = lane >> 4;
    int arow = base + r16;
    if (arow >= n) arow = n - 1;  // clamp loads; stores masked below
    const unsigned short* Arow = Sb + (size_t)arow * F;

    f32x4 acc[8];
#pragma unroll
    for (int i = 0; i < 8; ++i) acc[i] = (f32x4){0.f, 0.f, 0.f, 0.f};

#pragma unroll
    for (int s = 0; s < 4; ++s) {
        const bf16x8 a = *(const bf16x8*)(Arow + s * 32 + hi * 8);
#pragma unroll
        for (int nn = 0; nn < 8; ++nn) {
            const bf16x8 b = *(const bf16x8*)(Wfrag + ((size_t)(s * 8 + nn) * 64 + lane) * 8);
            acc[nn] = __builtin_amdgcn_mfma_f32_16x16x32_bf16(a, b, acc[nn], 0, 0, 0);
        }
    }

#pragma unroll
    for (int nn = 0; nn < 8; ++nn) {
        const int col = nn * 16 + r16;
        const float bv = bias[col];
#pragma unroll
        for (int r = 0; r < 4; ++r) {
            const int row = base + hi * 4 + r;
            if (row < n) {
                float v = acc[nn][r] + bv;
                if (relu) v = fmaxf(v, 0.f);
                Hb[(size_t)row * F + col] = f2bf(v);
            }
        }
    }
}

// ---------------- layer-3 transform first (linearity): y = h @ W3 ----------
__global__ __launch_bounds__(256) void head_t(const ushort2* __restrict__ Hb,
                                              const float4* __restrict__ W3,
                                              float2* __restrict__ y, int n) {
    const int wid = (blockIdx.x * blockDim.x + threadIdx.x) >> 6;
    const int lane = threadIdx.x & 63;
    if (wid >= n) return;
    const float2 h = up2(Hb[(size_t)wid * 64 + lane]);
    const float4 w = W3[lane];
    float a0 = h.x * w.x + h.y * w.z;
    float a1 = h.x * w.y + h.y * w.w;
#pragma unroll
    for (int o = 32; o; o >>= 1) {
        a0 += __shfl_xor(a0, o);
        a1 += __shfl_xor(a1, o);
    }
    if (lane == 0) y[wid] = make_float2(a0, a1);
}

// ---------------- layer-3 aggregation on 2-dim y: out = y + agg(y) + b3 -----
__global__ __launch_bounds__(256) void agg3(const float2* __restrict__ y,
                                            const int* __restrict__ off,
                                            const unsigned short* __restrict__ ssrc,
                                            const float* __restrict__ b3,
                                            float2* __restrict__ out, int n) {
    const int i = blockIdx.x * blockDim.x + threadIdx.x;
    if (i >= n) return;
    float2 acc = y[i];
    const int e1 = off[i + 1];
    for (int e = off[i]; e < e1; ++e) {
        const float2 v = y[ssrc[e]];
        acc.x += v.x;
        acc.y += v.y;
    }
    out[i] = make_float2(acc.x + b3[0], acc.y + b3[1]);
}

extern "C" void kernel_launch(void* const* d_in, const int* in_sizes, int n_in,
                              void* d_out, int out_size, void* d_ws, size_t ws_size,
                              hipStream_t stream) {
    const float* x  = (const float*)d_in[0];
    const int* ei   = (const int*)d_in[1];
    const int* src  = ei;
    const int* dst  = ei + NEDGES;
    const float* W1 = (const float*)d_in[2];
    const float* b1 = (const float*)d_in[3];
    const float* W2 = (const float*)d_in[4];
    const float* b2 = (const float*)d_in[5];
    const float* W3 = (const float*)d_in[6];
    const float* b3 = (const float*)d_in[7];
    float* out = (float*)d_out;

    char* ws = (char*)d_ws;
    const size_t featB = (size_t)NNODES * F * 2;  // 12.8 MB
    unsigned short* xb = (unsigned short*)ws;                 // bf16 x; reused for H2
    unsigned short* Sb = (unsigned short*)(ws + featB);       // aggregated (bf16)
    unsigned short* Hb = (unsigned short*)(ws + 2 * featB);   // layer-1 output
    char* p = ws + 3 * featB;
    float* y3 = (float*)p;                 p += (size_t)NNODES * 2 * 4 + 256;
    unsigned short* Wf1 = (unsigned short*)p; p += 2048 * 8 * 2;
    unsigned short* Wf2 = (unsigned short*)p; p += 2048 * 8 * 2;
    unsigned* E1 = (unsigned*)p;           p += (size_t)NB * BCAP * 4;
    int* gcnt = (int*)p;                   p += NB * 4;
    int* bstart = (int*)p;                 p += (NB + 1) * 4 + 256;
    int* off = (int*)p;                    p += (size_t)(NNODES + 1) * 4 + 256;
    unsigned short* ssrc = (unsigned short*)p;

    // ---- prep ----
    hipMemsetAsync(gcnt, 0, NB * sizeof(int), stream);
    cvt_bf16<<<1024, 256, 0, stream>>>((const float4*)x, (ushort4*)xb, NNODES * F / 4);
    wprep2<<<16, 256, 0, stream>>>(W1, W2, Wf1, Wf2);

    // ---- CSR build: bucketed two-phase counting sort ----
    bucketA<<<NEDGES / (256 * EPT), 256, 0, stream>>>(src, dst, E1, gcnt);
    scanB<<<1, 64, 0, stream>>>(gcnt, bstart, off);
    bucketB<<<NB, 256, 0, stream>>>(E1, gcnt, bstart, off, ssrc);

    const int aggBlocks = (NNODES + 3) / 4;
    const int mlpBlocks = (NNODES + 63) / 64;

    // ---- layer 1 ----
    agg_bf16<<<aggBlocks, 256, 0, stream>>>((const ushort2*)xb, off, ssrc, (ushort2*)Sb, NNODES);
    mlp_mfma<<<mlpBlocks, 256, 0, stream>>>(Sb, Wf1, b1, Hb, NNODES, 1);

    // ---- layer 2 ----
    agg_bf16<<<aggBlocks, 256, 0, stream>>>((const ushort2*)Hb, off, ssrc, (ushort2*)Sb, NNODES);
    mlp_mfma<<<mlpBlocks, 256, 0, stream>>>(Sb, Wf2, b2, xb, NNODES, 1);

    // ---- layer 3: transform first (linearity), then 2-dim aggregation ----
    head_t<<<aggBlocks, 256, 0, stream>>>((const ushort2*)xb, (const float4*)W3, (float2*)y3, NNODES);
    agg3<<<(NNODES + 255) / 256, 256, 0, stream>>>((const float2*)y3, off, ssrc, b3, (float2*)out, NNODES);
}

// Round 6
// 291.333 us; speedup vs baseline: 28.3330x; 1.0794x over previous
//
#include <hip/hip_runtime.h>

#define NNODES 50000
#define NEDGES 1600000
#define F 128

#define NB 128        // coarse buckets
#define BSH 391       // nodes per bucket (128*391 = 50048 >= 50000)
#define BCAP 13312    // slots per bucket (mean 12500, +6.5 sigma)
#define EPT 10        // edges per thread in bucketA (625 * 2560 = 1600000 exactly)

typedef __attribute__((ext_vector_type(8))) short bf16x8;
typedef __attribute__((ext_vector_type(4))) float f32x4;

__device__ inline unsigned short f2bf(float f) {
    union { float f; unsigned u; } v; v.f = f;
    unsigned r = v.u + 0x7FFF + ((v.u >> 16) & 1);  // RNE
    return (unsigned short)(r >> 16);
}
__device__ inline float2 up2(ushort2 h) {
    union { unsigned u; float f; } a, b;
    a.u = ((unsigned)h.x) << 16; b.u = ((unsigned)h.y) << 16;
    return make_float2(a.f, b.f);
}

// ---------------- f32 -> bf16 feature conversion ----------------
__global__ __launch_bounds__(256) void cvt_bf16(const float4* __restrict__ in,
                                                ushort4* __restrict__ out, int n4) {
    int i = blockIdx.x * blockDim.x + threadIdx.x;
    int stride = gridDim.x * blockDim.x;
    for (; i < n4; i += stride) {
        float4 v = in[i];
        ushort4 o;
        o.x = f2bf(v.x); o.y = f2bf(v.y); o.z = f2bf(v.z); o.w = f2bf(v.w);
        out[i] = o;
    }
}

// ---------------- pack W1,W2 into MFMA B-fragment order; zero gcnt ----------
// frag(s,n), lane l, j=0..7:  B[k = s*32 + (l>>4)*8 + j][c = n*16 + (l&15)]
__global__ __launch_bounds__(256) void wprep2(const float* __restrict__ W1,
                                              const float* __restrict__ W2,
                                              unsigned short* __restrict__ Wf1,
                                              unsigned short* __restrict__ Wf2,
                                              int* __restrict__ gcnt) {
    int id = blockIdx.x * 256 + threadIdx.x;  // 0..4095
    if (blockIdx.x == 0 && threadIdx.x < NB) gcnt[threadIdx.x] = 0;
    const float* W = (id < 2048) ? W1 : W2;
    unsigned short* Wf = (id < 2048) ? Wf1 : Wf2;
    id &= 2047;
    const int l = id & 63, nn = (id >> 6) & 7, s = id >> 9;
    const int c = nn * 16 + (l & 15);
    const int k0 = s * 32 + (l >> 4) * 8;
    ushort4 lo, hi;
    lo.x = f2bf(W[(k0 + 0) * F + c]); lo.y = f2bf(W[(k0 + 1) * F + c]);
    lo.z = f2bf(W[(k0 + 2) * F + c]); lo.w = f2bf(W[(k0 + 3) * F + c]);
    hi.x = f2bf(W[(k0 + 4) * F + c]); hi.y = f2bf(W[(k0 + 5) * F + c]);
    hi.z = f2bf(W[(k0 + 6) * F + c]); hi.w = f2bf(W[(k0 + 7) * F + c]);
    ushort4* p = (ushort4*)(Wf + (size_t)id * 8);
    p[0] = lo; p[1] = hi;
}

// ---------------- phase A: multi-split edges into 128 coarse buckets --------
// rec = (src << 9) | (dst % BSH); bucket = dst / BSH.
// Per-WAVE LDS histograms/cursors (4x less same-address contention), one
// global atomicAdd per (tile,bucket), chunked writes from a single CU.
__global__ __launch_bounds__(256) void bucketA(const int* __restrict__ src,
                                               const int* __restrict__ dst,
                                               unsigned* __restrict__ E1,
                                               int* __restrict__ gcnt) {
    __shared__ unsigned hist[4][NB];
    __shared__ unsigned start[4][NB];
    const int t = threadIdx.x, w = t >> 6;
    for (int i = t; i < 4 * NB; i += 256) ((unsigned*)hist)[i] = 0;
    __syncthreads();
    const int base = blockIdx.x * (256 * EPT);
    unsigned rec[EPT]; int bkt[EPT];
#pragma unroll
    for (int k = 0; k < EPT; ++k) {
        const int i = base + k * 256 + t;  // coalesced
        const int s = src[i], d = dst[i];
        const int b = d / BSH;             // const divide -> magic mul
        rec[k] = ((unsigned)s << 9) | (unsigned)(d - b * BSH);
        bkt[k] = b;
        atomicAdd(&hist[w][b], 1u);
    }
    __syncthreads();
    if (t < NB) {
        const unsigned h0 = hist[0][t], h1 = hist[1][t], h2 = hist[2][t], h3 = hist[3][t];
        const unsigned tot = h0 + h1 + h2 + h3;
        const unsigned g = tot ? (unsigned)atomicAdd(&gcnt[t], (int)tot) : 0u;
        start[0][t] = g;
        start[1][t] = g + h0;
        start[2][t] = g + h0 + h1;
        start[3][t] = g + h0 + h1 + h2;
        hist[0][t] = 0; hist[1][t] = 0; hist[2][t] = 0; hist[3][t] = 0;
    }
    __syncthreads();
#pragma unroll
    for (int k = 0; k < EPT; ++k) {
        const int b = bkt[k];
        const unsigned p = start[w][b] + atomicAdd(&hist[w][b], 1u);
        if (p < BCAP) E1[(size_t)b * BCAP + p] = rec[k];
    }
}

// ---------------- phase B: in-LDS counting sort per bucket -> exact CSR -----
// Bucket starts computed in-block by a one-wave scan of gcnt (scanB folded in).
__global__ __launch_bounds__(256) void bucketB(const unsigned* __restrict__ E1,
                                               const int* __restrict__ gcnt,
                                               int* __restrict__ off,
                                               unsigned short* __restrict__ ssrc) {
    __shared__ int cnt[BSH];
    __shared__ int cur[BSH];
    __shared__ int wtot[4];
    __shared__ int bst[NB];
    const int b = blockIdx.x, t = threadIdx.x;
    // one-wave exclusive scan of the 128 bucket counts
    if (t < 64) {
        const int a0 = gcnt[t * 2], a1 = gcnt[t * 2 + 1];
        const int s = a0 + a1;
        int inc = s;
#pragma unroll
        for (int o = 1; o <= 32; o <<= 1) {
            int u = __shfl_up(inc, o);
            if (t >= o) inc += u;
        }
        bst[t * 2] = inc - s;
        bst[t * 2 + 1] = inc - s + a0;
    }
    for (int i = t; i < BSH; i += 256) cnt[i] = 0;
    __syncthreads();
    const int ne = min(gcnt[b], BCAP);
    const int ebase = bst[b];
    const unsigned* E = E1 + (size_t)b * BCAP;
    for (int i = t; i < ne; i += 256) atomicAdd(&cnt[E[i] & 511], 1);
    __syncthreads();
    // exclusive scan of cnt[0..BSH), 2 elements per thread
    const int i0 = t * 2, i1 = t * 2 + 1;
    const int a0 = (i0 < BSH) ? cnt[i0] : 0;
    const int a1 = (i1 < BSH) ? cnt[i1] : 0;
    const int s = a0 + a1;
    int inc = s;
    const int lane = t & 63, w = t >> 6;
#pragma unroll
    for (int o = 1; o <= 32; o <<= 1) {
        int u = __shfl_up(inc, o);
        if (lane >= o) inc += u;
    }
    if (lane == 63) wtot[w] = inc;
    __syncthreads();
    int woff = 0;
    for (int k = 0; k < w; ++k) woff += wtot[k];  // w <= 3
    const int excl = woff + inc - s;
    if (i0 < BSH) {
        cur[i0] = excl;
        const int n = b * BSH + i0;
        if (n < NNODES) off[n] = ebase + excl;
    }
    if (i1 < BSH) {
        cur[i1] = excl + a0;
        const int n = b * BSH + i1;
        if (n < NNODES) off[n] = ebase + excl + a0;
    }
    if (b == NB - 1 && t == 0) off[NNODES] = NEDGES;
    __syncthreads();
    for (int i = t; i < ne; i += 256) {
        const unsigned rec = E[i];
        const int r = atomicAdd(&cur[rec & 511], 1);
        ssrc[ebase + r] = (unsigned short)(rec >> 9);
    }
}

// ---------------- aggregation (bf16): S[i] = h[i] + sum h[ssrc[e]] ------
// One wave per node. Indices loaded coalesced (2B/lane per 64 edges), then
// broadcast via __shfl; 8 gathers kept in flight.
__global__ __launch_bounds__(256) void agg_bf16(const ushort2* __restrict__ h,
                                                const int* __restrict__ off,
                                                const unsigned short* __restrict__ ssrc,
                                                ushort2* __restrict__ S, int n) {
    const int wid = (blockIdx.x * blockDim.x + threadIdx.x) >> 6;
    const int lane = threadIdx.x & 63;
    if (wid >= n) return;
    const int e0 = off[wid], e1 = off[wid + 1];
    float2 acc = up2(h[(size_t)wid * 64 + lane]);
    for (int base = e0; base < e1; base += 64) {
        const int cnt = min(64, e1 - base);
        const int myidx = (base + lane < e1) ? (int)ssrc[base + lane] : 0;
        int i = 0;
        for (; i + 8 <= cnt; i += 8) {
            const int s0 = __shfl(myidx, i + 0), s1 = __shfl(myidx, i + 1);
            const int s2 = __shfl(myidx, i + 2), s3 = __shfl(myidx, i + 3);
            const int s4 = __shfl(myidx, i + 4), s5 = __shfl(myidx, i + 5);
            const int s6 = __shfl(myidx, i + 6), s7 = __shfl(myidx, i + 7);
            const float2 v0 = up2(h[(size_t)s0 * 64 + lane]);
            const float2 v1 = up2(h[(size_t)s1 * 64 + lane]);
            const float2 v2 = up2(h[(size_t)s2 * 64 + lane]);
            const float2 v3 = up2(h[(size_t)s3 * 64 + lane]);
            const float2 v4 = up2(h[(size_t)s4 * 64 + lane]);
            const float2 v5 = up2(h[(size_t)s5 * 64 + lane]);
            const float2 v6 = up2(h[(size_t)s6 * 64 + lane]);
            const float2 v7 = up2(h[(size_t)s7 * 64 + lane]);
            acc.x += ((v0.x + v1.x) + (v2.x + v3.x)) + ((v4.x + v5.x) + (v6.x + v7.x));
            acc.y += ((v0.y + v1.y) + (v2.y + v3.y)) + ((v4.y + v5.y) + (v6.y + v7.y));
        }
        for (; i < cnt; ++i) {
            const int s = __shfl(myidx, i);
            const float2 v = up2(h[(size_t)s * 64 + lane]);
            acc.x += v.x;
            acc.y += v.y;
        }
    }
    ushort2 o;
    o.x = f2bf(acc.x); o.y = f2bf(acc.y);
    S[(size_t)wid * 64 + lane] = o;
}

// ---------------- MFMA MLP: Hb = relu?(Sb @ W + b)  [M=n, N=128, K=128] -----
__global__ __launch_bounds__(256) void mlp_mfma(const unsigned short* __restrict__ Sb,
                                                const unsigned short* __restrict__ Wfrag,
                                                const float* __restrict__ bias,
                                                unsigned short* __restrict__ Hb,
                                                int n, int relu) {
    const int wave = threadIdx.x >> 6, lane = threadIdx.x & 63;
    const int base = blockIdx.x * 64 + wave * 16;
    const int r16 = lane & 15, hi = lane >> 4;
    int arow = base + r16;
    if (arow >= n) arow = n - 1;  // clamp loads; stores masked below
    const unsigned short* Arow = Sb + (size_t)arow * F;

    f32x4 acc[8];
#pragma unroll
    for (int i = 0; i < 8; ++i) acc[i] = (f32x4){0.f, 0.f, 0.f, 0.f};

#pragma unroll
    for (int s = 0; s < 4; ++s) {
        const bf16x8 a = *(const bf16x8*)(Arow + s * 32 + hi * 8);
#pragma unroll
        for (int nn = 0; nn < 8; ++nn) {
            const bf16x8 b = *(const bf16x8*)(Wfrag + ((size_t)(s * 8 + nn) * 64 + lane) * 8);
            acc[nn] = __builtin_amdgcn_mfma_f32_16x16x32_bf16(a, b, acc[nn], 0, 0, 0);
        }
    }

#pragma unroll
    for (int nn = 0; nn < 8; ++nn) {
        const int col = nn * 16 + r16;
        const float bv = bias[col];
#pragma unroll
        for (int r = 0; r < 4; ++r) {
            const int row = base + hi * 4 + r;
            if (row < n) {
                float v = acc[nn][r] + bv;
                if (relu) v = fmaxf(v, 0.f);
                Hb[(size_t)row * F + col] = f2bf(v);
            }
        }
    }
}

// ---------------- layer-3 transform first (linearity): y = h @ W3 ----------
__global__ __launch_bounds__(256) void head_t(const ushort2* __restrict__ Hb,
                                              const float4* __restrict__ W3,
                                              float2* __restrict__ y, int n) {
    const int wid = (blockIdx.x * blockDim.x + threadIdx.x) >> 6;
    const int lane = threadIdx.x & 63;
    if (wid >= n) return;
    const float2 h = up2(Hb[(size_t)wid * 64 + lane]);
    const float4 w = W3[lane];
    float a0 = h.x * w.x + h.y * w.z;
    float a1 = h.x * w.y + h.y * w.w;
#pragma unroll
    for (int o = 32; o; o >>= 1) {
        a0 += __shfl_xor(a0, o);
        a1 += __shfl_xor(a1, o);
    }
    if (lane == 0) y[wid] = make_float2(a0, a1);
}

// ---------------- layer-3 aggregation on 2-dim y: out = y + agg(y) + b3 -----
__global__ __launch_bounds__(256) void agg3(const float2* __restrict__ y,
                                            const int* __restrict__ off,
                                            const unsigned short* __restrict__ ssrc,
                                            const float* __restrict__ b3,
                                            float2* __restrict__ out, int n) {
    const int i = blockIdx.x * blockDim.x + threadIdx.x;
    if (i >= n) return;
    float2 acc = y[i];
    const int e1 = off[i + 1];
    for (int e = off[i]; e < e1; ++e) {
        const float2 v = y[ssrc[e]];
        acc.x += v.x;
        acc.y += v.y;
    }
    out[i] = make_float2(acc.x + b3[0], acc.y + b3[1]);
}

extern "C" void kernel_launch(void* const* d_in, const int* in_sizes, int n_in,
                              void* d_out, int out_size, void* d_ws, size_t ws_size,
                              hipStream_t stream) {
    const float* x  = (const float*)d_in[0];
    const int* ei   = (const int*)d_in[1];
    const int* src  = ei;
    const int* dst  = ei + NEDGES;
    const float* W1 = (const float*)d_in[2];
    const float* b1 = (const float*)d_in[3];
    const float* W2 = (const float*)d_in[4];
    const float* b2 = (const float*)d_in[5];
    const float* W3 = (const float*)d_in[6];
    const float* b3 = (const float*)d_in[7];
    float* out = (float*)d_out;

    char* ws = (char*)d_ws;
    const size_t featB = (size_t)NNODES * F * 2;  // 12.8 MB
    unsigned short* xb = (unsigned short*)ws;                 // bf16 x; reused for H2
    unsigned short* Sb = (unsigned short*)(ws + featB);       // aggregated (bf16)
    unsigned short* Hb = (unsigned short*)(ws + 2 * featB);   // layer-1 output
    char* p = ws + 3 * featB;
    float* y3 = (float*)p;                 p += (size_t)NNODES * 2 * 4 + 256;
    unsigned short* Wf1 = (unsigned short*)p; p += 2048 * 8 * 2;
    unsigned short* Wf2 = (unsigned short*)p; p += 2048 * 8 * 2;
    unsigned* E1 = (unsigned*)p;           p += (size_t)NB * BCAP * 4;
    int* gcnt = (int*)p;                   p += NB * 4 + 256;
    int* off = (int*)p;                    p += (size_t)(NNODES + 1) * 4 + 256;
    unsigned short* ssrc = (unsigned short*)p;

    // ---- prep ----
    cvt_bf16<<<1024, 256, 0, stream>>>((const float4*)x, (ushort4*)xb, NNODES * F / 4);
    wprep2<<<16, 256, 0, stream>>>(W1, W2, Wf1, Wf2, gcnt);

    // ---- CSR build: bucketed two-phase counting sort ----
    bucketA<<<NEDGES / (256 * EPT), 256, 0, stream>>>(src, dst, E1, gcnt);
    bucketB<<<NB, 256, 0, stream>>>(E1, gcnt, off, ssrc);

    const int aggBlocks = (NNODES + 3) / 4;
    const int mlpBlocks = (NNODES + 63) / 64;

    // ---- layer 1 ----
    agg_bf16<<<aggBlocks, 256, 0, stream>>>((const ushort2*)xb, off, ssrc, (ushort2*)Sb, NNODES);
    mlp_mfma<<<mlpBlocks, 256, 0, stream>>>(Sb, Wf1, b1, Hb, NNODES, 1);

    // ---- layer 2 ----
    agg_bf16<<<aggBlocks, 256, 0, stream>>>((const ushort2*)Hb, off, ssrc, (ushort2*)Sb, NNODES);
    mlp_mfma<<<mlpBlocks, 256, 0, stream>>>(Sb, Wf2, b2, xb, NNODES, 1);

    // ---- layer 3: transform first (linearity), then 2-dim aggregation ----
    head_t<<<aggBlocks, 256, 0, stream>>>((const ushort2*)xb, (const float4*)W3, (float2*)y3, NNODES);
    agg3<<<(NNODES + 255) / 256, 256, 0, stream>>>((const float2*)y3, off, ssrc, b3, (float2*)out, NNODES);
}